// Round 7
// baseline (414.652 us; speedup 1.0000x reference)
//
#include <hip/hip_runtime.h>
#include <hip/hip_bf16.h>
#include <stdint.h>

// GNNStream pipeline. GEMM core (gemm_bt): bf16 MFMA 16x16x32, 128x128 tile,
// BK=32 ping-pong double-buffered LDS (4 x 8KB buffers, constant 32KB), XOR-
// swizzled panels (R4/R5: verified 0 bank conflicts), global_load_lds(16B),
// LDS-staged coalesced bf16 epilogue.
//   Prefetch(panel p+1) issued AFTER barrier, BEFORE compute(panel p): each
//   barrier drains loads that had a full compute phase to land (latency hide).
//   Epilogue i-loop MUST be fully unrolled: dynamic indexing of acc -> scratch
//   spill (R3: VGPR 88->52, 3.5 GB HBM, 676 us).
// mask is int32 on device (harness: integer -> const int*).

typedef __hip_bfloat16 bf16_t;
typedef __attribute__((ext_vector_type(8))) short bf16x8;
typedef __attribute__((ext_vector_type(4))) float f32x4;

__device__ __forceinline__ void cp16_to_lds(const void* g, void* lds) {
  __builtin_amdgcn_global_load_lds(
      (__attribute__((address_space(1))) void*)(g),
      (__attribute__((address_space(3))) void*)(lds), 16, 0, 0);
}

__device__ __forceinline__ uint pk2(float a, float b) {
  bf16_t x = __float2bfloat16(a), y = __float2bfloat16(b);
  return ((uint)(*(ushort*)&y) << 16) | (*(ushort*)&x);
}
__device__ __forceinline__ float bflo(uint u) { return __uint_as_float(u << 16); }
__device__ __forceinline__ float bfhi(uint u) { return __uint_as_float(u & 0xffff0000u); }

// C = A * B^T (+bias) * scale.  A: M x K row-major, B: N x K row-major, bf16.
// mode 0: bf16 out via LDS-staged coalesced stores. mode 2: f32 out.
__global__ __launch_bounds__(256) void gemm_bt(
    const bf16_t* __restrict__ A, const bf16_t* __restrict__ B,
    void* __restrict__ Cv, const float* __restrict__ bias, int biasStride,
    float scale, int K, long sA, long sB, long sC, int ldC, int mode)
{
  __shared__ __align__(16) char smem[32768];
  // layout: A-buf0 @0, A-buf1 @8192, B-buf0 @16384, B-buf1 @24576
  bf16_t* lA = (bf16_t*)smem;
  bf16_t* lB = (bf16_t*)(smem + 16384);
  const int z = blockIdx.z;
  A += (long)z * sA;
  B += (long)z * sB;
  const float* bz = bias ? bias + (long)z * biasStride : nullptr;
  const int m0 = blockIdx.y * 128, n0 = blockIdx.x * 128;
  const int tid = threadIdx.x;
  const int w = tid >> 6, lane = tid & 63;
  const int wm = w >> 1, wn = w & 1;

  // staging (per 128x32 panel): lane loads global chunk (tid&3)^s(row) -> phys
  // chunk tid&3.  s(row) = (row>>1)&3; row = tid>>2 (+64 for second cp).
  const int rr = tid >> 2;
  const int cc = (((tid & 3) ^ ((tid >> 3) & 3)) * 8);
  const bf16_t* a0 = A + (long)(m0 + rr) * K + cc;
  const bf16_t* b0 = B + (long)(n0 + rr) * K + cc;
  const long rowskip = (long)64 * K;

  char* lAc = (char*)lA;
  char* lBc = (char*)lB;
  const int ofs0 = w * 1024;
  const int ofs1 = 4096 + w * 1024;

  f32x4 acc[4][4] = {};
  const int quad = lane >> 4;
  const int rsel = lane & 15;
  const int swz = (rsel >> 1) & 3;
  const int kchunkA = (quad ^ swz) * 8;

#define STAGE(kofs, bofs) do {                                   \
    cp16_to_lds(a0 + (kofs),           lAc + (bofs) + ofs0);     \
    cp16_to_lds(a0 + (kofs) + rowskip, lAc + (bofs) + ofs1);     \
    cp16_to_lds(b0 + (kofs),           lBc + (bofs) + ofs0);     \
    cp16_to_lds(b0 + (kofs) + rowskip, lBc + (bofs) + ofs1);     \
  } while (0)

#define COMPUTE(pbase) do {                                                        \
    bf16x8 af[4], bfr[4];                                                          \
    _Pragma("unroll")                                                              \
    for (int i = 0; i < 4; ++i) {                                                  \
      af[i]  = *(const bf16x8*)&lA[(pbase) + (wm * 64 + i * 16 + rsel) * 32 + kchunkA]; \
      bfr[i] = *(const bf16x8*)&lB[(pbase) + (wn * 64 + i * 16 + rsel) * 32 + kchunkA]; \
    }                                                                              \
    _Pragma("unroll")                                                              \
    for (int i = 0; i < 4; ++i)                                                    \
      _Pragma("unroll")                                                            \
      for (int j = 0; j < 4; ++j)                                                  \
        acc[i][j] = __builtin_amdgcn_mfma_f32_16x16x32_bf16(af[i], bfr[j], acc[i][j], 0, 0, 0); \
  } while (0)

  const int npan = K >> 5;            // #BK=32 panels; K%64==0 so npan even
  STAGE(0, 0);                        // prologue: panel 0 -> buf0
  for (int pp = 0; pp < npan; pp += 2) {
    __syncthreads();                  // drains stage(panel pp -> buf0)
    STAGE((pp + 1) * 32, 8192);       // prefetch panel pp+1 -> buf1
    COMPUTE(0);                       // compute panel pp from buf0
    __syncthreads();                  // drains stage(panel pp+1)
    if (pp + 2 < npan) STAGE((pp + 2) * 32, 0);   // prefetch -> buf0
    COMPUTE(4096);                    // compute panel pp+1 from buf1
  }
#undef STAGE
#undef COMPUTE

  const int col = lane & 15;
  float bv4[4];
#pragma unroll
  for (int j = 0; j < 4; ++j) {
    const int ng = n0 + wn * 64 + j * 16 + col;
    bv4[j] = bz ? bz[ng] : 0.0f;
  }

  if (mode == 0) {
    char* stb = smem + w * 2176;      // 16 rows x 68 bf16 (136B stride)
    const int nc0 = n0 + wn * 64;
#pragma unroll
    for (int i = 0; i < 4; ++i) {     // FULLY UNROLLED (R3 lesson)
      __syncthreads();
      bf16_t* st = (bf16_t*)stb;
#pragma unroll
      for (int j = 0; j < 4; ++j)
#pragma unroll
        for (int r = 0; r < 4; ++r)
          st[(quad * 4 + r) * 68 + j * 16 + col] =
              __float2bfloat16(acc[i][j][r] * scale + bv4[j]);
      __syncthreads();
      const int row16 = lane >> 2, cseg = lane & 3;
      const long mrow = m0 + wm * 64 + i * 16 + row16;
      bf16_t* cp = (bf16_t*)Cv + (long)z * sC + mrow * ldC + nc0 + cseg * 16;
      const char* sp = stb + row16 * 136 + cseg * 32;
#pragma unroll
      for (int hh = 0; hh < 2; ++hh) {
        uint2 aa = *(const uint2*)(sp + hh * 16);
        uint2 bb = *(const uint2*)(sp + hh * 16 + 8);
        uint4 vv; vv.x = aa.x; vv.y = aa.y; vv.z = bb.x; vv.w = bb.y;
        *(uint4*)(cp + hh * 8) = vv;
      }
    }
  } else {
#pragma unroll
    for (int j = 0; j < 4; ++j) {
      const int ng = n0 + wn * 64 + j * 16 + col;
#pragma unroll
      for (int i = 0; i < 4; ++i) {
        const int mg = m0 + wm * 64 + i * 16 + quad * 4;
#pragma unroll
        for (int r = 0; r < 4; ++r)
          ((float*)Cv)[(long)z * sC + (long)(mg + r) * ldC + ng] =
              acc[i][j][r] * scale + bv4[j];
      }
    }
  }
}

// All weight transposes (512 x N f32 -> N x 512 bf16) in one launch.
// z: 0=wenc 1=wq 2=wk 3=wv (N=512), 4=wbn (N=256). Output slot stride 262144 elems.
// Also gathers bq/bk/bv into bias_cat[3*512].
__global__ __launch_bounds__(256) void weight_prep(
    const float* __restrict__ w0, const float* __restrict__ w1,
    const float* __restrict__ w2, const float* __restrict__ w3,
    const float* __restrict__ w4,
    const float* __restrict__ bq, const float* __restrict__ bk,
    const float* __restrict__ bv,
    bf16_t* __restrict__ outT, float* __restrict__ bias_cat)
{
  const int z = blockIdx.z;
  const int N = (z == 4) ? 256 : 512;
  if (z == 4 && blockIdx.y >= 4) return;
  const float* in = (z == 0) ? w0 : (z == 1) ? w1 : (z == 2) ? w2 : (z == 3) ? w3 : w4;
  bf16_t* out = outT + (long)z * 262144;
  const int k0 = blockIdx.x * 64, n0 = blockIdx.y * 64;
  __shared__ bf16_t tile[64 * 66];
  const int tid = threadIdx.x;
  const int r = tid >> 2, c4 = tid & 3;
  const float* src = in + (long)(k0 + r) * N + n0 + c4 * 16;
  uint* dst = (uint*)&tile[r * 66 + c4 * 16];
  float4 f0 = ((const float4*)src)[0], f1 = ((const float4*)src)[1];
  float4 f2 = ((const float4*)src)[2], f3 = ((const float4*)src)[3];
  dst[0] = pk2(f0.x, f0.y); dst[1] = pk2(f0.z, f0.w);
  dst[2] = pk2(f1.x, f1.y); dst[3] = pk2(f1.z, f1.w);
  dst[4] = pk2(f2.x, f2.y); dst[5] = pk2(f2.z, f2.w);
  dst[6] = pk2(f3.x, f3.y); dst[7] = pk2(f3.z, f3.w);
  __syncthreads();
  bf16_t* og = out + (long)(n0 + r) * 512 + k0 + c4 * 16;
  uint ov[8];
#pragma unroll
  for (int j = 0; j < 16; j += 2) {
    const ushort lo = *(const ushort*)&tile[(c4 * 16 + j) * 66 + r];
    const ushort hi = *(const ushort*)&tile[(c4 * 16 + j + 1) * 66 + r];
    ov[j >> 1] = ((uint)hi << 16) | lo;
  }
  uint4 o0, o1;
  o0.x = ov[0]; o0.y = ov[1]; o0.z = ov[2]; o0.w = ov[3];
  o1.x = ov[4]; o1.y = ov[5]; o1.z = ov[6]; o1.w = ov[7];
  ((uint4*)og)[0] = o0;
  ((uint4*)og)[1] = o1;
  if (z >= 1 && z <= 3 && blockIdx.x == 0 && blockIdx.y == 0) {
    const float* bs = (z == 1) ? bq : (z == 2) ? bk : bv;
    bias_cat[(z - 1) * 512 + tid] = bs[tid];
    bias_cat[(z - 1) * 512 + 256 + tid] = bs[256 + tid];
  }
}

// v [8*2048 x 512] bf16 -> vT [8][512][2048] bf16, 64x64 tiles, padded LDS
__global__ __launch_bounds__(256) void transpose_bf16_k(
    const bf16_t* __restrict__ in, bf16_t* __restrict__ o)
{
  __shared__ bf16_t tile[64 * 66];
  const int b = blockIdx.z, t0 = blockIdx.x * 64, d0 = blockIdx.y * 64;
  const int tid = threadIdx.x;
  const int r = tid >> 2, c4 = tid & 3;
  const uint4* src = (const uint4*)(in + ((long)b * 2048 + t0 + r) * 512 + d0 + c4 * 16);
  uint* dst = (uint*)&tile[r * 66 + c4 * 16];
  uint4 g0 = src[0], g1 = src[1];
  dst[0] = g0.x; dst[1] = g0.y; dst[2] = g0.z; dst[3] = g0.w;
  dst[4] = g1.x; dst[5] = g1.y; dst[6] = g1.z; dst[7] = g1.w;
  __syncthreads();
  bf16_t* dstg = o + ((long)b * 512 + d0 + r) * 2048 + t0 + c4 * 16;
  uint ov[8];
#pragma unroll
  for (int k = 0; k < 16; k += 2) {
    const ushort lo = *(const ushort*)&tile[(c4 * 16 + k) * 66 + r];
    const ushort hi = *(const ushort*)&tile[(c4 * 16 + k + 1) * 66 + r];
    ov[k >> 1] = ((uint)hi << 16) | lo;
  }
  uint4 o0, o1;
  o0.x = ov[0]; o0.y = ov[1]; o0.z = ov[2]; o0.w = ov[3];
  o1.x = ov[4]; o1.y = ov[5]; o1.z = ov[6]; o1.w = ov[7];
  ((uint4*)dstg)[0] = o0;
  ((uint4*)dstg)[1] = o1;
}

// f32 -> bf16, 4 elems/thread
__global__ __launch_bounds__(256) void cast_bf16_v(
    const float4* __restrict__ in, uint2* __restrict__ o, int n4) {
  const int i = blockIdx.x * 256 + threadIdx.x;
  if (i < n4) {
    const float4 f = in[i];
    uint2 r; r.x = pk2(f.x, f.y); r.y = pk2(f.z, f.w);
    o[i] = r;
  }
}

// in-place LayerNorm(512)+ReLU, one wave per row, 8 bf16/lane, shuffle-only.
__global__ __launch_bounds__(256) void ln_relu_h(
    bf16_t* __restrict__ X, const float* __restrict__ g, const float* __restrict__ b)
{
  const int tid = threadIdx.x;
  const int lane = tid & 63, w = tid >> 6;
  const long row = (long)blockIdx.x * 4 + w;
  bf16_t* xp = X + row * 512 + lane * 8;
  const uint4 pkv = *(const uint4*)xp;
  const uint va[4] = {pkv.x, pkv.y, pkv.z, pkv.w};
  float v[8];
  float s = 0.0f, q = 0.0f;
#pragma unroll
  for (int i = 0; i < 4; ++i) {
    v[2 * i] = bflo(va[i]); v[2 * i + 1] = bfhi(va[i]);
    s += v[2 * i] + v[2 * i + 1];
    q += v[2 * i] * v[2 * i] + v[2 * i + 1] * v[2 * i + 1];
  }
  for (int o = 32; o; o >>= 1) { s += __shfl_down(s, o); q += __shfl_down(q, o); }
  s = __shfl(s, 0); q = __shfl(q, 0);
  const float mu = s * (1.0f / 512.0f);
  const float rs = rsqrtf(q * (1.0f / 512.0f) - mu * mu + 1e-5f);
  const float4 g0 = ((const float4*)(g + lane * 8))[0], g1 = ((const float4*)(g + lane * 8))[1];
  const float4 b0 = ((const float4*)(b + lane * 8))[0], b1 = ((const float4*)(b + lane * 8))[1];
  const float gg[8] = {g0.x, g0.y, g0.z, g0.w, g1.x, g1.y, g1.z, g1.w};
  const float bb[8] = {b0.x, b0.y, b0.z, b0.w, b1.x, b1.y, b1.z, b1.w};
  uint ov[4];
#pragma unroll
  for (int i = 0; i < 4; ++i) {
    const float y0 = fmaxf((v[2 * i] - mu) * rs * gg[2 * i] + bb[2 * i], 0.0f);
    const float y1 = fmaxf((v[2 * i + 1] - mu) * rs * gg[2 * i + 1] + bb[2 * i + 1], 0.0f);
    ov[i] = pk2(y0, y1);
  }
  uint4 st; st.x = ov[0]; st.y = ov[1]; st.z = ov[2]; st.w = ov[3];
  *(uint4*)xp = st;
}

// per row: softmax over 2048, then * exp(-5*dist) * (!mask), in-place bf16.
__global__ __launch_bounds__(256) void softmax_adj(
    bf16_t* __restrict__ SC, const float* __restrict__ coords,
    const int* __restrict__ mask)
{
  const int bs = blockIdx.x;
  const int b = bs >> 11, s = bs & 2047;
  const long base = (long)bs * 2048;
  const int tid = threadIdx.x;
  const uint4 pkv = *(const uint4*)(SC + base + tid * 8);
  const uint va[4] = {pkv.x, pkv.y, pkv.z, pkv.w};
  float rv[8];
  float mx = -3.0e38f;
#pragma unroll
  for (int i = 0; i < 4; ++i) {
    rv[2 * i] = bflo(va[i]); rv[2 * i + 1] = bfhi(va[i]);
    mx = fmaxf(mx, fmaxf(rv[2 * i], rv[2 * i + 1]));
  }
  for (int o = 32; o; o >>= 1) mx = fmaxf(mx, __shfl_down(mx, o));
  __shared__ float sm[8];
  const int w = tid >> 6, lane = tid & 63;
  if (!lane) sm[w] = mx;
  __syncthreads();
  mx = fmaxf(fmaxf(sm[0], sm[1]), fmaxf(sm[2], sm[3]));
  float sum = 0.0f;
#pragma unroll
  for (int i = 0; i < 8; ++i) { rv[i] = __expf(rv[i] - mx); sum += rv[i]; }
  for (int o = 32; o; o >>= 1) sum += __shfl_down(sum, o);
  if (!lane) sm[4 + w] = sum;
  __syncthreads();
  const float inv = 1.0f / (sm[4] + sm[5] + sm[6] + sm[7]);
  const float px = coords[((long)b * 2048 + s) * 3];
  const float py = coords[((long)b * 2048 + s) * 3 + 1];
  const int t0 = tid * 8;
  const float* cb = coords + ((long)b * 2048 + t0) * 3;
  const int* mb = mask + b * 2048 + t0;
  uint ov[4];
#pragma unroll
  for (int i = 0; i < 8; ++i) {
    const float dx = px - cb[i * 3], dy = py - cb[i * 3 + 1];
    const float adj = __expf(-5.0f * sqrtf(dx * dx + dy * dy));
    const float val = mb[i] ? 0.0f : rv[i] * inv * adj;
    bf16_t bt = __float2bfloat16(val);
    const ushort u = *(const ushort*)&bt;
    if (i & 1) ov[i >> 1] |= ((uint)u << 16);
    else       ov[i >> 1] = u;
  }
  uint4 st; st.x = ov[0]; st.y = ov[1]; st.z = ov[2]; st.w = ov[3];
  *(uint4*)(SC + base + t0) = st;
}

// LayerNorm(256)+ReLU on f32 rows, masked accumulate into pooled_acc[b][256]
__global__ __launch_bounds__(256) void ln2_pool(
    const float* __restrict__ X, const float* __restrict__ g, const float* __restrict__ bt,
    const int* __restrict__ mask, float* __restrict__ pacc)
{
  const int tid = threadIdx.x;
  const int row0 = blockIdx.x * 16;
  const int w = tid >> 6, lane = tid & 63;
  __shared__ float sm[8];
  const float gv = g[tid], bv = bt[tid];
  float acc = 0.0f;
  for (int r = 0; r < 16; ++r) {
    const int row = row0 + r;
    const float x = X[(long)row * 256 + tid];
    float s = x, q = x * x;
    for (int o = 32; o; o >>= 1) { s += __shfl_down(s, o); q += __shfl_down(q, o); }
    if (!lane) { sm[w] = s; sm[4 + w] = q; }
    __syncthreads();
    const float S = sm[0] + sm[1] + sm[2] + sm[3];
    const float Q = sm[4] + sm[5] + sm[6] + sm[7];
    const float mu = S * (1.0f / 256.0f);
    const float rs = rsqrtf(Q * (1.0f / 256.0f) - mu * mu + 1e-5f);
    const float y = fmaxf((x - mu) * rs * gv + bv, 0.0f);
    if (!mask[row]) acc += y;
    __syncthreads();
  }
  atomicAdd(&pacc[(row0 >> 11) * 256 + tid], acc);
}

// counts, pooled=acc/count -> out[80..], relu(pooled@w1+b1)@w2+b2 -> out[0..80)
__global__ __launch_bounds__(256) void classifier_k(
    const float* __restrict__ pacc, const int* __restrict__ mask,
    const float* __restrict__ w1, const float* __restrict__ b1,
    const float* __restrict__ w2, const float* __restrict__ b2,
    float* __restrict__ out)
{
  const int tid = threadIdx.x;
  __shared__ float pooled[2048];
  __shared__ float hidden[1024];
  __shared__ float cnt[8];
  if (tid < 8) cnt[tid] = 0.0f;
  __syncthreads();
  {
    const int* mb = mask + tid * 64;
    int c = 0;
#pragma unroll 8
    for (int i = 0; i < 64; ++i) c += mb[i] ? 0 : 1;
    atomicAdd(&cnt[tid >> 5], (float)c);
  }
  __syncthreads();
  for (int i = tid; i < 2048; i += 256) {
    const float p = pacc[i] / fmaxf(cnt[i >> 8], 1e-9f);
    pooled[i] = p;
    out[80 + i] = p;
  }
  __syncthreads();
  for (int o = tid; o < 1024; o += 256) {
    const int bb = o >> 7, j = o & 127;
    float s = b1[j];
    const float* pb = pooled + bb * 256;
    for (int c = 0; c < 256; ++c) s += pb[c] * w1[c * 128 + j];
    hidden[o] = fmaxf(s, 0.0f);
  }
  __syncthreads();
  if (tid < 80) {
    const int bb = tid / 10, j = tid - bb * 10;
    float s = b2[j];
    const float* hb = hidden + bb * 128;
    for (int c = 0; c < 128; ++c) s += hb[c] * w2[c * 10 + j];
    out[tid] = s;
  }
}

extern "C" void kernel_launch(void* const* d_in, const int* in_sizes, int n_in,
                              void* d_out, int out_size, void* d_ws, size_t ws_size,
                              hipStream_t stream)
{
  const float* lf   = (const float*)d_in[0];
  const float* co   = (const float*)d_in[1];
  const int*   mk   = (const int*)d_in[2];
  const float* wenc = (const float*)d_in[3];
  const float* benc = (const float*)d_in[4];
  const float* g1   = (const float*)d_in[5];
  const float* be1  = (const float*)d_in[6];
  const float* wq   = (const float*)d_in[7];
  const float* bq   = (const float*)d_in[8];
  const float* wk   = (const float*)d_in[9];
  const float* bk   = (const float*)d_in[10];
  const float* wv   = (const float*)d_in[11];
  const float* bvp  = (const float*)d_in[12];
  const float* wbn  = (const float*)d_in[13];
  const float* bbn  = (const float*)d_in[14];
  const float* g2   = (const float*)d_in[15];
  const float* be2  = (const float*)d_in[16];
  const float* w1   = (const float*)d_in[17];
  const float* b1   = (const float*)d_in[18];
  const float* w2   = (const float*)d_in[19];
  const float* b2   = (const float*)d_in[20];
  float* out = (float*)d_out;
  char* ws = (char*)d_ws;

  // Layout (bytes). Reuse: hg overlays featb (dead after enc GEMM);
  // bnp overlays q (dead after scores); pacc overlays k region.
  bf16_t* featb = (bf16_t*)(ws + 0);              // 16 MB
  bf16_t* wT    = (bf16_t*)(ws + 16777216);       // 5 x 512KB slots (wbn half-used)
  bf16_t* wencT = wT;
  bf16_t* wqT   = wT + 262144;
  bf16_t* wbnT  = wT + 4 * 262144;
  float*  bias_cat = (float*)(ws + 19398656);     // 6 KB
  bf16_t* h     = (bf16_t*)(ws + 19404800);       // 16 MB
  bf16_t* qkv   = (bf16_t*)(ws + 36182016);       // 48 MB (q, k, v)
  bf16_t* vT    = (bf16_t*)(ws + 86513664);       // 16 MB
  bf16_t* sc    = (bf16_t*)(ws + 103290880);      // 64 MB, ends 170399744
  bf16_t* hg    = (bf16_t*)(ws + 0);              // reuse featb
  float*  bnp   = (float*)(ws + 36182016);        // reuse q slot (16 MB f32)
  float*  pacc  = (float*)(ws + 52959232);        // reuse k slot head (8 KB)

  if (ws_size < 170399744) return;  // fail visibly rather than fault

  cast_bf16_v<<<8192, 256, 0, stream>>>((const float4*)lf, (uint2*)featb, 2097152);
  weight_prep<<<dim3(8, 8, 5), 256, 0, stream>>>(wenc, wq, wk, wv, wbn, bq, bk, bvp,
                                                 wT, bias_cat);

  // h_pre = feat @ w_enc + b_enc
  gemm_bt<<<dim3(4, 128, 1), 256, 0, stream>>>(featb, wencT, h, benc, 0, 1.0f, 512,
                                               0, 0, 0, 512, 0);
  ln_relu_h<<<4096, 256, 0, stream>>>(h, g1, be1);
  // q,k,v in one launch: z selects weight slot / bias / output slot
  gemm_bt<<<dim3(4, 128, 3), 256, 0, stream>>>(h, wqT, qkv, bias_cat, 512, 1.0f, 512,
                                               0, 262144, 8388608, 512, 0);
  transpose_bf16_k<<<dim3(32, 8, 8), 256, 0, stream>>>(qkv + 16777216, vT);
  // scores[b] = q_b k_b^T / sqrt(512)
  gemm_bt<<<dim3(16, 16, 8), 256, 0, stream>>>(qkv, qkv + 8388608, sc, nullptr, 0,
                                               0.044194173824159216f, 512,
                                               1048576, 1048576, 4194304, 2048, 0);
  softmax_adj<<<16384, 256, 0, stream>>>(sc, co, mk);
  // hg[b] = attn_b @ v_b   (B = vT, N=512, K=2048)
  gemm_bt<<<dim3(4, 16, 8), 256, 0, stream>>>(sc, vT, hg, nullptr, 0, 1.0f, 2048,
                                              4194304, 1048576, 1048576, 512, 0);
  // bn_pre = hg @ w_bn + b_bn  (f32 out)
  gemm_bt<<<dim3(2, 128, 1), 256, 0, stream>>>(hg, wbnT, bnp, bbn, 0, 1.0f, 512,
                                               0, 0, 0, 256, 2);
  hipMemsetAsync(pacc, 0, 8192, stream);
  ln2_pool<<<1024, 256, 0, stream>>>(bnp, g2, be2, mk, pacc);
  classifier_k<<<1, 256, 0, stream>>>(pacc, mk, w1, b1, w2, b2, out);
}

// Round 8
// 365.345 us; speedup vs baseline: 1.1350x; 1.1350x over previous
//
#include <hip/hip_runtime.h>
#include <hip/hip_bf16.h>
#include <stdint.h>

// GNNStream pipeline.
// gemm_bt (bf16): R6-verified core. MFMA 16x16x32_bf16, 128x128 tile, BK=64 as
//   2x BK=32 XOR-swizzled panels (0 bank conflicts), global_load_lds(16B),
//   LDS-staged coalesced epilogue. R7 ping-pong dbuf was NEUTRAL (m99/m131
//   replication) -> reverted.
// gemm_qkv: same core; epilogue writes q,k as fp8 e4m3 (HW cvt_pk) and v
//   transposed (vT[b][d][t]) via per-wave LDS staging.
// gemm_sc_fp8: scores GEMM on fp8 q,k. mfma_f32_16x16x32_fp8_fp8, BK=128 as
//   2x (128row x 64B) panels -> same staging geometry as bf16-BK32; 4-way b64
//   read conflicts accepted (half bytes vs bf16 nets ~0.8x LDS-pipe time).
// Epilogue loops MUST be fully unrolled: dynamic acc indexing -> scratch spill
//   (R3: VGPR 88->52, 3.5 GB HBM, 676 us).
// mask is int32 on device (harness: integer -> const int*).

typedef __hip_bfloat16 bf16_t;
typedef unsigned char u8;
typedef __attribute__((ext_vector_type(8))) short bf16x8;
typedef __attribute__((ext_vector_type(4))) float f32x4;

__device__ __forceinline__ void cp16_to_lds(const void* g, void* lds) {
  __builtin_amdgcn_global_load_lds(
      (__attribute__((address_space(1))) void*)(g),
      (__attribute__((address_space(3))) void*)(lds), 16, 0, 0);
}

__device__ __forceinline__ uint pk2(float a, float b) {
  bf16_t x = __float2bfloat16(a), y = __float2bfloat16(b);
  return ((uint)(*(ushort*)&y) << 16) | (*(ushort*)&x);
}
__device__ __forceinline__ float bflo(uint u) { return __uint_as_float(u << 16); }
__device__ __forceinline__ float bfhi(uint u) { return __uint_as_float(u & 0xffff0000u); }

// ---------------- bf16 GEMM (R6 core) ----------------
// C = A * B^T (+bias) * scale.  A: M x K row-major, B: N x K row-major, bf16.
// mode 0: bf16 out via LDS-staged coalesced stores. mode 2: f32 out.
__global__ __launch_bounds__(256) void gemm_bt(
    const bf16_t* __restrict__ A, const bf16_t* __restrict__ B,
    void* __restrict__ Cv, const float* __restrict__ bias, int biasStride,
    float scale, int K, long sA, long sB, long sC, int ldC, int mode)
{
  __shared__ __align__(16) char smem[32768];
  bf16_t* lA = (bf16_t*)smem;             // 2 panels x (128 rows x 32 k), swizzled
  bf16_t* lB = (bf16_t*)(smem + 16384);
  const int z = blockIdx.z;
  A += (long)z * sA;
  B += (long)z * sB;
  const float* bz = bias ? bias + (long)z * biasStride : nullptr;
  const int m0 = blockIdx.y * 128, n0 = blockIdx.x * 128;
  const int tid = threadIdx.x;
  const int w = tid >> 6, lane = tid & 63;
  const int wm = w >> 1, wn = w & 1;

  const int rr = tid >> 2;
  const int cc = (((tid & 3) ^ ((tid >> 3) & 3)) * 8);
  const bf16_t* a0 = A + (long)(m0 + rr) * K + cc;
  const bf16_t* b0 = B + (long)(n0 + rr) * K + cc;
  const long rowskip = (long)64 * K;

  char* lAc = (char*)lA;
  char* lBc = (char*)lB;
  const int ofs0 = w * 1024;
  const int ofs1 = 4096 + w * 1024;

  f32x4 acc[4][4] = {};
  const int nkt = K >> 6;             // BK=64
  const int quad = lane >> 4;
  const int rsel = lane & 15;
  const int swz = (rsel >> 1) & 3;
  const int kchunkA = (quad ^ swz) * 8;

  for (int kt = 0; kt < nkt; ++kt) {
    __syncthreads();
    cp16_to_lds(a0,                 lAc + ofs0);
    cp16_to_lds(a0 + rowskip,       lAc + ofs1);
    cp16_to_lds(a0 + 32,            lAc + 8192 + ofs0);
    cp16_to_lds(a0 + 32 + rowskip,  lAc + 8192 + ofs1);
    cp16_to_lds(b0,                 lBc + ofs0);
    cp16_to_lds(b0 + rowskip,       lBc + ofs1);
    cp16_to_lds(b0 + 32,            lBc + 8192 + ofs0);
    cp16_to_lds(b0 + 32 + rowskip,  lBc + 8192 + ofs1);
    a0 += 64; b0 += 64;
    __syncthreads();

#pragma unroll
    for (int p = 0; p < 2; ++p) {
      const int pb = p * 4096;
      bf16x8 af[4], bfr[4];
#pragma unroll
      for (int i = 0; i < 4; ++i) {
        af[i]  = *(const bf16x8*)&lA[pb + (wm * 64 + i * 16 + rsel) * 32 + kchunkA];
        bfr[i] = *(const bf16x8*)&lB[pb + (wn * 64 + i * 16 + rsel) * 32 + kchunkA];
      }
#pragma unroll
      for (int i = 0; i < 4; ++i)
#pragma unroll
        for (int j = 0; j < 4; ++j)
          acc[i][j] = __builtin_amdgcn_mfma_f32_16x16x32_bf16(af[i], bfr[j], acc[i][j], 0, 0, 0);
    }
  }

  const int col = lane & 15;
  float bv4[4];
#pragma unroll
  for (int j = 0; j < 4; ++j) {
    const int ng = n0 + wn * 64 + j * 16 + col;
    bv4[j] = bz ? bz[ng] : 0.0f;
  }

  if (mode == 0) {
    char* stb = smem + w * 2176;      // 16 rows x 68 bf16 (136B stride)
    const int nc0 = n0 + wn * 64;
#pragma unroll
    for (int i = 0; i < 4; ++i) {     // FULLY UNROLLED (R3 lesson)
      __syncthreads();
      bf16_t* st = (bf16_t*)stb;
#pragma unroll
      for (int j = 0; j < 4; ++j)
#pragma unroll
        for (int r = 0; r < 4; ++r)
          st[(quad * 4 + r) * 68 + j * 16 + col] =
              __float2bfloat16(acc[i][j][r] * scale + bv4[j]);
      __syncthreads();
      const int row16 = lane >> 2, cseg = lane & 3;
      const long mrow = m0 + wm * 64 + i * 16 + row16;
      bf16_t* cp = (bf16_t*)Cv + (long)z * sC + mrow * ldC + nc0 + cseg * 16;
      const char* sp = stb + row16 * 136 + cseg * 32;
#pragma unroll
      for (int hh = 0; hh < 2; ++hh) {
        uint2 aa = *(const uint2*)(sp + hh * 16);
        uint2 bb = *(const uint2*)(sp + hh * 16 + 8);
        uint4 vv; vv.x = aa.x; vv.y = aa.y; vv.z = bb.x; vv.w = bb.y;
        *(uint4*)(cp + hh * 8) = vv;
      }
    }
  } else {
#pragma unroll
    for (int j = 0; j < 4; ++j) {
      const int ng = n0 + wn * 64 + j * 16 + col;
#pragma unroll
      for (int i = 0; i < 4; ++i) {
        const int mg = m0 + wm * 64 + i * 16 + quad * 4;
#pragma unroll
        for (int r = 0; r < 4; ++r)
          ((float*)Cv)[(long)z * sC + (long)(mg + r) * ldC + ng] =
              acc[i][j][r] * scale + bv4[j];
      }
    }
  }
}

// ---------------- fused q/k/v GEMM ----------------
// A = h [16384x512] bf16, B = wT + (z+1)*262144, bias = bias_cat + z*512.
// z 0,1: write fp8 e4m3 to o8 + z*8388608 (natural [t][n], n=512).
// z 2  : write bf16 transposed to vT[b][d][t] (d=512, t=2048 per batch).
__global__ __launch_bounds__(256) void gemm_qkv(
    const bf16_t* __restrict__ A, const bf16_t* __restrict__ wT,
    const float* __restrict__ bias_cat, u8* __restrict__ o8,
    bf16_t* __restrict__ vT)
{
  __shared__ __align__(16) char smem[32768];
  bf16_t* lA = (bf16_t*)smem;
  bf16_t* lB = (bf16_t*)(smem + 16384);
  const int z = blockIdx.z;
  const bf16_t* B = wT + (long)(z + 1) * 262144;
  const float* bz = bias_cat + (long)z * 512;
  const int K = 512;
  const int m0 = blockIdx.y * 128, n0 = blockIdx.x * 128;
  const int tid = threadIdx.x;
  const int w = tid >> 6, lane = tid & 63;
  const int wm = w >> 1, wn = w & 1;

  const int rr = tid >> 2;
  const int cc = (((tid & 3) ^ ((tid >> 3) & 3)) * 8);
  const bf16_t* a0 = A + (long)(m0 + rr) * K + cc;
  const bf16_t* b0 = B + (long)(n0 + rr) * K + cc;
  const long rowskip = (long)64 * K;

  char* lAc = (char*)lA;
  char* lBc = (char*)lB;
  const int ofs0 = w * 1024;
  const int ofs1 = 4096 + w * 1024;

  f32x4 acc[4][4] = {};
  const int quad = lane >> 4;
  const int rsel = lane & 15;
  const int swz = (rsel >> 1) & 3;
  const int kchunkA = (quad ^ swz) * 8;

  for (int kt = 0; kt < 8; ++kt) {    // K=512 / BK=64
    __syncthreads();
    cp16_to_lds(a0,                 lAc + ofs0);
    cp16_to_lds(a0 + rowskip,       lAc + ofs1);
    cp16_to_lds(a0 + 32,            lAc + 8192 + ofs0);
    cp16_to_lds(a0 + 32 + rowskip,  lAc + 8192 + ofs1);
    cp16_to_lds(b0,                 lBc + ofs0);
    cp16_to_lds(b0 + rowskip,       lBc + ofs1);
    cp16_to_lds(b0 + 32,            lBc + 8192 + ofs0);
    cp16_to_lds(b0 + 32 + rowskip,  lBc + 8192 + ofs1);
    a0 += 64; b0 += 64;
    __syncthreads();

#pragma unroll
    for (int p = 0; p < 2; ++p) {
      const int pb = p * 4096;
      bf16x8 af[4], bfr[4];
#pragma unroll
      for (int i = 0; i < 4; ++i) {
        af[i]  = *(const bf16x8*)&lA[pb + (wm * 64 + i * 16 + rsel) * 32 + kchunkA];
        bfr[i] = *(const bf16x8*)&lB[pb + (wn * 64 + i * 16 + rsel) * 32 + kchunkA];
      }
#pragma unroll
      for (int i = 0; i < 4; ++i)
#pragma unroll
        for (int j = 0; j < 4; ++j)
          acc[i][j] = __builtin_amdgcn_mfma_f32_16x16x32_bf16(af[i], bfr[j], acc[i][j], 0, 0, 0);
    }
  }

  const int col = lane & 15;
  float bv4[4];
#pragma unroll
  for (int j = 0; j < 4; ++j) bv4[j] = bz[n0 + wn * 64 + j * 16 + col];
  const int nc0 = n0 + wn * 64;

  if (z < 2) {
    // fp8 out: per-wave staging 16 t-rows x 72B (64 fp8 + pad)
    u8* stb = (u8*)(smem + w * 2176);
    u8* O = o8 + (long)z * 8388608;
#pragma unroll
    for (int i = 0; i < 4; ++i) {
      __syncthreads();
#pragma unroll
      for (int j = 0; j < 4; ++j) {
        uint pk = 0;
        pk = __builtin_amdgcn_cvt_pk_fp8_f32(acc[i][j][0] + bv4[j],
                                             acc[i][j][1] + bv4[j], pk, false);
        pk = __builtin_amdgcn_cvt_pk_fp8_f32(acc[i][j][2] + bv4[j],
                                             acc[i][j][3] + bv4[j], pk, true);
        stb[(quad * 4 + 0) * 72 + j * 16 + col] = (u8)(pk);
        stb[(quad * 4 + 1) * 72 + j * 16 + col] = (u8)(pk >> 8);
        stb[(quad * 4 + 2) * 72 + j * 16 + col] = (u8)(pk >> 16);
        stb[(quad * 4 + 3) * 72 + j * 16 + col] = (u8)(pk >> 24);
      }
      __syncthreads();
      const int trow = lane >> 2, seg = lane & 3;
      const long mrow = m0 + wm * 64 + i * 16 + trow;
      *(uint4*)(O + mrow * 512 + nc0 + seg * 16) =
          *(const uint4*)(stb + trow * 72 + seg * 16);
    }
  } else {
    // vT out: per-wave staging 16 d-rows x 68 bf16 (136B stride, 8B aligned)
    bf16_t* st = (bf16_t*)(smem + w * 2176);
    const int bt = blockIdx.y >> 4;          // batch (16 y-blocks per batch)
    const int t0g = (m0 & 2047) + wm * 64;
#pragma unroll
    for (int j = 0; j < 4; ++j) {
      __syncthreads();
#pragma unroll
      for (int i = 0; i < 4; ++i) {
        uint2 v2;
        v2.x = pk2(acc[i][j][0] + bv4[j], acc[i][j][1] + bv4[j]);
        v2.y = pk2(acc[i][j][2] + bv4[j], acc[i][j][3] + bv4[j]);
        *(uint2*)&st[col * 68 + i * 16 + quad * 4] = v2;
      }
      __syncthreads();
      const int drow = lane >> 2, seg = lane & 3;
      const int d = nc0 + j * 16 + drow;
      bf16_t* dst = vT + ((long)(bt * 512 + d)) * 2048 + t0g;
#pragma unroll
      for (int rd = 0; rd < 2; ++rd)
        *(uint4*)(dst + rd * 32 + seg * 8) =
            *(const uint4*)((const char*)st + drow * 136 + rd * 64 + seg * 16);
    }
  }
}

// ---------------- fp8 scores GEMM ----------------
// sc[b] = q8_b k8_b^T * scale, K=512. A,B fp8 e4m3 [2048 x 512] per batch.
// BK=128 as 2 panels of (128 rows x 64B), staging identical geometry to bf16.
__global__ __launch_bounds__(256) void gemm_sc_fp8(
    const u8* __restrict__ A, const u8* __restrict__ B,
    bf16_t* __restrict__ C, float scale)
{
  __shared__ __align__(16) char smem[32768];
  const int K = 512;
  const int z = blockIdx.z;
  A += (long)z * 1048576;
  B += (long)z * 1048576;
  const int m0 = blockIdx.y * 128, n0 = blockIdx.x * 128;
  const int tid = threadIdx.x;
  const int w = tid >> 6, lane = tid & 63;
  const int wm = w >> 1, wn = w & 1;

  const int rr = tid >> 2;
  const int ccB = (((tid & 3) ^ ((tid >> 3) & 3)) * 16);   // byte ofs in 64B row
  const u8* a0 = A + (long)(m0 + rr) * K + ccB;
  const u8* b0 = B + (long)(n0 + rr) * K + ccB;
  const long rowskip = (long)64 * K;

  char* lAc = smem;
  char* lBc = smem + 16384;
  const int ofs0 = w * 1024;
  const int ofs1 = 4096 + w * 1024;

  f32x4 acc[4][4] = {};
  const int quad = lane >> 4;
  const int rsel = lane & 15;
  const int swz = (rsel >> 1) & 3;

  for (int kt = 0; kt < 4; ++kt) {    // K=512 / BK=128
    __syncthreads();
    cp16_to_lds(a0,                  lAc + ofs0);
    cp16_to_lds(a0 + rowskip,        lAc + ofs1);
    cp16_to_lds(a0 + 64,             lAc + 8192 + ofs0);
    cp16_to_lds(a0 + 64 + rowskip,   lAc + 8192 + ofs1);
    cp16_to_lds(b0,                  lBc + ofs0);
    cp16_to_lds(b0 + rowskip,        lBc + ofs1);
    cp16_to_lds(b0 + 64,             lBc + 8192 + ofs0);
    cp16_to_lds(b0 + 64 + rowskip,   lBc + 8192 + ofs1);
    a0 += 128; b0 += 128;
    __syncthreads();

#pragma unroll
    for (int p = 0; p < 2; ++p) {
      const int pb = p * 8192;
#pragma unroll
      for (int ks = 0; ks < 2; ++ks) {
        const int gr = ((ks * 2 + (quad >> 1)) ^ swz) * 16 + (quad & 1) * 8;
        long av[4], bv[4];
#pragma unroll
        for (int i = 0; i < 4; ++i) {
          av[i] = *(const long*)(lAc + pb + (wm * 64 + i * 16 + rsel) * 64 + gr);
          bv[i] = *(const long*)(lBc + pb + (wn * 64 + i * 16 + rsel) * 64 + gr);
        }
#pragma unroll
        for (int i = 0; i < 4; ++i)
#pragma unroll
          for (int j = 0; j < 4; ++j)
            acc[i][j] = __builtin_amdgcn_mfma_f32_16x16x32_fp8_fp8(av[i], bv[j], acc[i][j], 0, 0, 0);
      }
    }
  }

  // epilogue: bf16 out, LDS-staged (mode-0 style), no bias
  const int col = lane & 15;
  char* stb = smem + w * 2176;
  const int nc0 = n0 + wn * 64;
#pragma unroll
  for (int i = 0; i < 4; ++i) {
    __syncthreads();
    bf16_t* st = (bf16_t*)stb;
#pragma unroll
    for (int j = 0; j < 4; ++j)
#pragma unroll
      for (int r = 0; r < 4; ++r)
        st[(quad * 4 + r) * 68 + j * 16 + col] =
            __float2bfloat16(acc[i][j][r] * scale);
    __syncthreads();
    const int row16 = lane >> 2, cseg = lane & 3;
    const long mrow = m0 + wm * 64 + i * 16 + row16;
    bf16_t* cp = C + (long)z * 4194304 + mrow * 2048 + nc0 + cseg * 16;
    const char* sp = stb + row16 * 136 + cseg * 32;
#pragma unroll
    for (int hh = 0; hh < 2; ++hh) {
      uint2 aa = *(const uint2*)(sp + hh * 16);
      uint2 bb = *(const uint2*)(sp + hh * 16 + 8);
      uint4 vv; vv.x = aa.x; vv.y = aa.y; vv.z = bb.x; vv.w = bb.y;
      *(uint4*)(cp + hh * 8) = vv;
    }
  }
}

// ---------------- small kernels ----------------
// All weight transposes (512 x N f32 -> N x 512 bf16) in one launch.
// z: 0=wenc 1=wq 2=wk 3=wv (N=512), 4=wbn (N=256). Slot stride 262144 elems.
// Also gathers bq/bk/bv into bias_cat[3*512].
__global__ __launch_bounds__(256) void weight_prep(
    const float* __restrict__ w0, const float* __restrict__ w1,
    const float* __restrict__ w2, const float* __restrict__ w3,
    const float* __restrict__ w4,
    const float* __restrict__ bq, const float* __restrict__ bk,
    const float* __restrict__ bv,
    bf16_t* __restrict__ outT, float* __restrict__ bias_cat)
{
  const int z = blockIdx.z;
  const int N = (z == 4) ? 256 : 512;
  if (z == 4 && blockIdx.y >= 4) return;
  const float* in = (z == 0) ? w0 : (z == 1) ? w1 : (z == 2) ? w2 : (z == 3) ? w3 : w4;
  bf16_t* out = outT + (long)z * 262144;
  const int k0 = blockIdx.x * 64, n0 = blockIdx.y * 64;
  __shared__ bf16_t tile[64 * 66];
  const int tid = threadIdx.x;
  const int r = tid >> 2, c4 = tid & 3;
  const float* src = in + (long)(k0 + r) * N + n0 + c4 * 16;
  uint* dst = (uint*)&tile[r * 66 + c4 * 16];
  float4 f0 = ((const float4*)src)[0], f1 = ((const float4*)src)[1];
  float4 f2 = ((const float4*)src)[2], f3 = ((const float4*)src)[3];
  dst[0] = pk2(f0.x, f0.y); dst[1] = pk2(f0.z, f0.w);
  dst[2] = pk2(f1.x, f1.y); dst[3] = pk2(f1.z, f1.w);
  dst[4] = pk2(f2.x, f2.y); dst[5] = pk2(f2.z, f2.w);
  dst[6] = pk2(f3.x, f3.y); dst[7] = pk2(f3.z, f3.w);
  __syncthreads();
  bf16_t* og = out + (long)(n0 + r) * 512 + k0 + c4 * 16;
  uint ov[8];
#pragma unroll
  for (int j = 0; j < 16; j += 2) {
    const ushort lo = *(const ushort*)&tile[(c4 * 16 + j) * 66 + r];
    const ushort hi = *(const ushort*)&tile[(c4 * 16 + j + 1) * 66 + r];
    ov[j >> 1] = ((uint)hi << 16) | lo;
  }
  uint4 o0, o1;
  o0.x = ov[0]; o0.y = ov[1]; o0.z = ov[2]; o0.w = ov[3];
  o1.x = ov[4]; o1.y = ov[5]; o1.z = ov[6]; o1.w = ov[7];
  ((uint4*)og)[0] = o0;
  ((uint4*)og)[1] = o1;
  if (z >= 1 && z <= 3 && blockIdx.x == 0 && blockIdx.y == 0) {
    const float* bs = (z == 1) ? bq : (z == 2) ? bk : bv;
    bias_cat[(z - 1) * 512 + tid] = bs[tid];
    bias_cat[(z - 1) * 512 + 256 + tid] = bs[256 + tid];
  }
}

// f32 -> bf16, 4 elems/thread
__global__ __launch_bounds__(256) void cast_bf16_v(
    const float4* __restrict__ in, uint2* __restrict__ o, int n4) {
  const int i = blockIdx.x * 256 + threadIdx.x;
  if (i < n4) {
    const float4 f = in[i];
    uint2 r; r.x = pk2(f.x, f.y); r.y = pk2(f.z, f.w);
    o[i] = r;
  }
}

// in-place LayerNorm(512)+ReLU, one wave per row, 8 bf16/lane, shuffle-only.
__global__ __launch_bounds__(256) void ln_relu_h(
    bf16_t* __restrict__ X, const float* __restrict__ g, const float* __restrict__ b)
{
  const int tid = threadIdx.x;
  const int lane = tid & 63, w = tid >> 6;
  const long row = (long)blockIdx.x * 4 + w;
  bf16_t* xp = X + row * 512 + lane * 8;
  const uint4 pkv = *(const uint4*)xp;
  const uint va[4] = {pkv.x, pkv.y, pkv.z, pkv.w};
  float v[8];
  float s = 0.0f, q = 0.0f;
#pragma unroll
  for (int i = 0; i < 4; ++i) {
    v[2 * i] = bflo(va[i]); v[2 * i + 1] = bfhi(va[i]);
    s += v[2 * i] + v[2 * i + 1];
    q += v[2 * i] * v[2 * i] + v[2 * i + 1] * v[2 * i + 1];
  }
  for (int o = 32; o; o >>= 1) { s += __shfl_down(s, o); q += __shfl_down(q, o); }
  s = __shfl(s, 0); q = __shfl(q, 0);
  const float mu = s * (1.0f / 512.0f);
  const float rs = rsqrtf(q * (1.0f / 512.0f) - mu * mu + 1e-5f);
  const float4 g0 = ((const float4*)(g + lane * 8))[0], g1 = ((const float4*)(g + lane * 8))[1];
  const float4 b0 = ((const float4*)(b + lane * 8))[0], b1 = ((const float4*)(b + lane * 8))[1];
  const float gg[8] = {g0.x, g0.y, g0.z, g0.w, g1.x, g1.y, g1.z, g1.w};
  const float bb[8] = {b0.x, b0.y, b0.z, b0.w, b1.x, b1.y, b1.z, b1.w};
  uint ov[4];
#pragma unroll
  for (int i = 0; i < 4; ++i) {
    const float y0 = fmaxf((v[2 * i] - mu) * rs * gg[2 * i] + bb[2 * i], 0.0f);
    const float y1 = fmaxf((v[2 * i + 1] - mu) * rs * gg[2 * i + 1] + bb[2 * i + 1], 0.0f);
    ov[i] = pk2(y0, y1);
  }
  uint4 st; st.x = ov[0]; st.y = ov[1]; st.z = ov[2]; st.w = ov[3];
  *(uint4*)xp = st;
}

// per row: softmax over 2048, then * exp(-5*dist) * (!mask), in-place bf16.
__global__ __launch_bounds__(256) void softmax_adj(
    bf16_t* __restrict__ SC, const float* __restrict__ coords,
    const int* __restrict__ mask)
{
  const int bs = blockIdx.x;
  const int b = bs >> 11, s = bs & 2047;
  const long base = (long)bs * 2048;
  const int tid = threadIdx.x;
  const uint4 pkv = *(const uint4*)(SC + base + tid * 8);
  const uint va[4] = {pkv.x, pkv.y, pkv.z, pkv.w};
  float rv[8];
  float mx = -3.0e38f;
#pragma unroll
  for (int i = 0; i < 4; ++i) {
    rv[2 * i] = bflo(va[i]); rv[2 * i + 1] = bfhi(va[i]);
    mx = fmaxf(mx, fmaxf(rv[2 * i], rv[2 * i + 1]));
  }
  for (int o = 32; o; o >>= 1) mx = fmaxf(mx, __shfl_down(mx, o));
  __shared__ float sm[8];
  const int w = tid >> 6, lane = tid & 63;
  if (!lane) sm[w] = mx;
  __syncthreads();
  mx = fmaxf(fmaxf(sm[0], sm[1]), fmaxf(sm[2], sm[3]));
  float sum = 0.0f;
#pragma unroll
  for (int i = 0; i < 8; ++i) { rv[i] = __expf(rv[i] - mx); sum += rv[i]; }
  for (int o = 32; o; o >>= 1) sum += __shfl_down(sum, o);
  if (!lane) sm[4 + w] = sum;
  __syncthreads();
  const float inv = 1.0f / (sm[4] + sm[5] + sm[6] + sm[7]);
  const float px = coords[((long)b * 2048 + s) * 3];
  const float py = coords[((long)b * 2048 + s) * 3 + 1];
  const int t0 = tid * 8;
  const float* cb = coords + ((long)b * 2048 + t0) * 3;
  const int* mb = mask + b * 2048 + t0;
  uint ov[4];
#pragma unroll
  for (int i = 0; i < 8; ++i) {
    const float dx = px - cb[i * 3], dy = py - cb[i * 3 + 1];
    const float adj = __expf(-5.0f * sqrtf(dx * dx + dy * dy));
    const float val = mb[i] ? 0.0f : rv[i] * inv * adj;
    bf16_t bt = __float2bfloat16(val);
    const ushort u = *(const ushort*)&bt;
    if (i & 1) ov[i >> 1] |= ((uint)u << 16);
    else       ov[i >> 1] = u;
  }
  uint4 st; st.x = ov[0]; st.y = ov[1]; st.z = ov[2]; st.w = ov[3];
  *(uint4*)(SC + base + t0) = st;
}

// LayerNorm(256)+ReLU on f32 rows, masked accumulate into pooled_acc[b][256]
__global__ __launch_bounds__(256) void ln2_pool(
    const float* __restrict__ X, const float* __restrict__ g, const float* __restrict__ bt,
    const int* __restrict__ mask, float* __restrict__ pacc)
{
  const int tid = threadIdx.x;
  const int row0 = blockIdx.x * 16;
  const int w = tid >> 6, lane = tid & 63;
  __shared__ float sm[8];
  const float gv = g[tid], bv = bt[tid];
  float acc = 0.0f;
  for (int r = 0; r < 16; ++r) {
    const int row = row0 + r;
    const float x = X[(long)row * 256 + tid];
    float s = x, q = x * x;
    for (int o = 32; o; o >>= 1) { s += __shfl_down(s, o); q += __shfl_down(q, o); }
    if (!lane) { sm[w] = s; sm[4 + w] = q; }
    __syncthreads();
    const float S = sm[0] + sm[1] + sm[2] + sm[3];
    const float Q = sm[4] + sm[5] + sm[6] + sm[7];
    const float mu = S * (1.0f / 256.0f);
    const float rs = rsqrtf(Q * (1.0f / 256.0f) - mu * mu + 1e-5f);
    const float y = fmaxf((x - mu) * rs * gv + bv, 0.0f);
    if (!mask[row]) acc += y;
    __syncthreads();
  }
  atomicAdd(&pacc[(row0 >> 11) * 256 + tid], acc);
}

// counts, pooled=acc/count -> out[80..], relu(pooled@w1+b1)@w2+b2 -> out[0..80)
__global__ __launch_bounds__(256) void classifier_k(
    const float* __restrict__ pacc, const int* __restrict__ mask,
    const float* __restrict__ w1, const float* __restrict__ b1,
    const float* __restrict__ w2, const float* __restrict__ b2,
    float* __restrict__ out)
{
  const int tid = threadIdx.x;
  __shared__ float pooled[2048];
  __shared__ float hidden[1024];
  __shared__ float cnt[8];
  if (tid < 8) cnt[tid] = 0.0f;
  __syncthreads();
  {
    const int* mb = mask + tid * 64;
    int c = 0;
#pragma unroll 8
    for (int i = 0; i < 64; ++i) c += mb[i] ? 0 : 1;
    atomicAdd(&cnt[tid >> 5], (float)c);
  }
  __syncthreads();
  for (int i = tid; i < 2048; i += 256) {
    const float p = pacc[i] / fmaxf(cnt[i >> 8], 1e-9f);
    pooled[i] = p;
    out[80 + i] = p;
  }
  __syncthreads();
  for (int o = tid; o < 1024; o += 256) {
    const int bb = o >> 7, j = o & 127;
    float s = b1[j];
    const float* pb = pooled + bb * 256;
    for (int c = 0; c < 256; ++c) s += pb[c] * w1[c * 128 + j];
    hidden[o] = fmaxf(s, 0.0f);
  }
  __syncthreads();
  if (tid < 80) {
    const int bb = tid / 10, j = tid - bb * 10;
    float s = b2[j];
    const float* hb = hidden + bb * 128;
    for (int c = 0; c < 128; ++c) s += hb[c] * w2[c * 10 + j];
    out[tid] = s;
  }
}

extern "C" void kernel_launch(void* const* d_in, const int* in_sizes, int n_in,
                              void* d_out, int out_size, void* d_ws, size_t ws_size,
                              hipStream_t stream)
{
  const float* lf   = (const float*)d_in[0];
  const float* co   = (const float*)d_in[1];
  const int*   mk   = (const int*)d_in[2];
  const float* wenc = (const float*)d_in[3];
  const float* benc = (const float*)d_in[4];
  const float* g1   = (const float*)d_in[5];
  const float* be1  = (const float*)d_in[6];
  const float* wq   = (const float*)d_in[7];
  const float* bq   = (const float*)d_in[8];
  const float* wk   = (const float*)d_in[9];
  const float* bk   = (const float*)d_in[10];
  const float* wv   = (const float*)d_in[11];
  const float* bvp  = (const float*)d_in[12];
  const float* wbn  = (const float*)d_in[13];
  const float* bbn  = (const float*)d_in[14];
  const float* g2   = (const float*)d_in[15];
  const float* be2  = (const float*)d_in[16];
  const float* w1   = (const float*)d_in[17];
  const float* b1   = (const float*)d_in[18];
  const float* w2   = (const float*)d_in[19];
  const float* b2   = (const float*)d_in[20];
  float* out = (float*)d_out;
  char* ws = (char*)d_ws;

  // Layout (bytes). Reuse: hg overlays featb (dead after enc GEMM);
  // bnp overlays q8+k8 (dead after scores); pacc overlays vT head (dead after attn.v).
  bf16_t* featb = (bf16_t*)(ws + 0);              // 16 MB
  bf16_t* wT    = (bf16_t*)(ws + 16777216);       // 5 x 512KB slots
  bf16_t* wencT = wT;
  bf16_t* wbnT  = wT + 4 * 262144;
  float*  bias_cat = (float*)(ws + 19398656);     // 6 KB
  bf16_t* h     = (bf16_t*)(ws + 19404800);       // 16 MB -> ends 36182016
  u8*     q8    = (u8*)(ws + 36182016);           // 8 MB (q,k fp8: 2 x 8388608)
  bf16_t* vT    = (bf16_t*)(ws + 52959232);       // 16 MB -> ends 69736448
  bf16_t* sc    = (bf16_t*)(ws + 69736448);       // 64 MB -> ends 136845312
  bf16_t* hg    = (bf16_t*)(ws + 0);              // reuse featb
  float*  bnp   = (float*)(ws + 36182016);        // reuse q8/k8 (16 MB f32)
  float*  pacc  = (float*)(ws + 52959232);        // reuse vT head (8 KB)

  if (ws_size < 136845312) return;  // fail visibly rather than fault

  cast_bf16_v<<<8192, 256, 0, stream>>>((const float4*)lf, (uint2*)featb, 2097152);
  weight_prep<<<dim3(8, 8, 5), 256, 0, stream>>>(wenc, wq, wk, wv, wbn, bq, bk, bvp,
                                                 wT, bias_cat);

  // h_pre = feat @ w_enc + b_enc
  gemm_bt<<<dim3(4, 128, 1), 256, 0, stream>>>(featb, wencT, h, benc, 0, 1.0f, 512,
                                               0, 0, 0, 512, 0);
  ln_relu_h<<<4096, 256, 0, stream>>>(h, g1, be1);
  // q,k (fp8) + v (bf16 transposed) in one launch
  gemm_qkv<<<dim3(4, 128, 3), 256, 0, stream>>>(h, wT, bias_cat, q8, vT);
  // scores[b] = q_b k_b^T / sqrt(512)  (fp8 inputs, bf16 out)
  gemm_sc_fp8<<<dim3(16, 16, 8), 256, 0, stream>>>(q8, q8 + 8388608, sc,
                                                   0.044194173824159216f);
  softmax_adj<<<16384, 256, 0, stream>>>(sc, co, mk);
  // hg[b] = attn_b @ v_b   (B = vT, N=512, K=2048)
  gemm_bt<<<dim3(4, 16, 8), 256, 0, stream>>>(sc, vT, hg, nullptr, 0, 1.0f, 2048,
                                              4194304, 1048576, 1048576, 512, 0);
  // bn_pre = hg @ w_bn + b_bn  (f32 out)
  gemm_bt<<<dim3(2, 128, 1), 256, 0, stream>>>(hg, wbnT, bnp, bbn, 0, 1.0f, 512,
                                               0, 0, 0, 256, 2);
  hipMemsetAsync(pacc, 0, 8192, stream);
  ln2_pool<<<1024, 256, 0, stream>>>(bnp, g2, be2, mk, pacc);
  classifier_k<<<1, 256, 0, stream>>>(pacc, mk, w1, b1, w2, b2, out);
}

// Round 9
// 364.619 us; speedup vs baseline: 1.1372x; 1.0020x over previous
//
#include <hip/hip_runtime.h>
#include <hip/hip_bf16.h>
#include <stdint.h>

// GNNStream pipeline.
// gemm_bt (bf16): R6-verified core. MFMA 16x16x32_bf16, 128x128 tile, BK=64 as
//   2x BK=32 XOR-swizzled panels (0 bank conflicts), global_load_lds(16B),
//   LDS-staged coalesced epilogue.
// gemm_qkv: same core; epilogue writes q,k fp8 e4m3 and v fp8 TRANSPOSED
//   (vT8[b][d][t]).
// gemm_fp8: generalized fp8 GEMM (scores q8 k8^T -> sc bf16; attn8 vT8 -> hg
//   bf16). mfma_f32_16x16x32_fp8_fp8, BK=128 as 2x 64B-row panels; XOR swizzle
//   at 16B granularity spreads banks (R8: no conflict blowup observed).
// softmax_adj: reads sc bf16, writes attn8 = fp8(attn * 256) -- mean attn
//   ~5e-4 is below e4m3 subnormal floor 2^-9, so x256 scale is mandatory;
//   gemm_fp8 epilogue folds 1/256 into its output scale.
// Epilogue loops MUST be fully unrolled: dynamic acc indexing -> scratch spill
//   (R3: VGPR 88->52, 3.5 GB HBM, 676 us).
// mask is int32 on device (harness: integer -> const int*).

typedef __hip_bfloat16 bf16_t;
typedef unsigned char u8;
typedef __attribute__((ext_vector_type(8))) short bf16x8;
typedef __attribute__((ext_vector_type(4))) float f32x4;

__device__ __forceinline__ void cp16_to_lds(const void* g, void* lds) {
  __builtin_amdgcn_global_load_lds(
      (__attribute__((address_space(1))) void*)(g),
      (__attribute__((address_space(3))) void*)(lds), 16, 0, 0);
}

__device__ __forceinline__ uint pk2(float a, float b) {
  bf16_t x = __float2bfloat16(a), y = __float2bfloat16(b);
  return ((uint)(*(ushort*)&y) << 16) | (*(ushort*)&x);
}
__device__ __forceinline__ float bflo(uint u) { return __uint_as_float(u << 16); }
__device__ __forceinline__ float bfhi(uint u) { return __uint_as_float(u & 0xffff0000u); }

// ---------------- bf16 GEMM (R6 core) ----------------
// C = A * B^T (+bias) * scale.  A: M x K row-major, B: N x K row-major, bf16.
// mode 0: bf16 out via LDS-staged coalesced stores. mode 2: f32 out.
__global__ __launch_bounds__(256) void gemm_bt(
    const bf16_t* __restrict__ A, const bf16_t* __restrict__ B,
    void* __restrict__ Cv, const float* __restrict__ bias, int biasStride,
    float scale, int K, long sA, long sB, long sC, int ldC, int mode)
{
  __shared__ __align__(16) char smem[32768];
  bf16_t* lA = (bf16_t*)smem;
  bf16_t* lB = (bf16_t*)(smem + 16384);
  const int z = blockIdx.z;
  A += (long)z * sA;
  B += (long)z * sB;
  const float* bz = bias ? bias + (long)z * biasStride : nullptr;
  const int m0 = blockIdx.y * 128, n0 = blockIdx.x * 128;
  const int tid = threadIdx.x;
  const int w = tid >> 6, lane = tid & 63;
  const int wm = w >> 1, wn = w & 1;

  const int rr = tid >> 2;
  const int cc = (((tid & 3) ^ ((tid >> 3) & 3)) * 8);
  const bf16_t* a0 = A + (long)(m0 + rr) * K + cc;
  const bf16_t* b0 = B + (long)(n0 + rr) * K + cc;
  const long rowskip = (long)64 * K;

  char* lAc = (char*)lA;
  char* lBc = (char*)lB;
  const int ofs0 = w * 1024;
  const int ofs1 = 4096 + w * 1024;

  f32x4 acc[4][4] = {};
  const int nkt = K >> 6;             // BK=64
  const int quad = lane >> 4;
  const int rsel = lane & 15;
  const int swz = (rsel >> 1) & 3;
  const int kchunkA = (quad ^ swz) * 8;

  for (int kt = 0; kt < nkt; ++kt) {
    __syncthreads();
    cp16_to_lds(a0,                 lAc + ofs0);
    cp16_to_lds(a0 + rowskip,       lAc + ofs1);
    cp16_to_lds(a0 + 32,            lAc + 8192 + ofs0);
    cp16_to_lds(a0 + 32 + rowskip,  lAc + 8192 + ofs1);
    cp16_to_lds(b0,                 lBc + ofs0);
    cp16_to_lds(b0 + rowskip,       lBc + ofs1);
    cp16_to_lds(b0 + 32,            lBc + 8192 + ofs0);
    cp16_to_lds(b0 + 32 + rowskip,  lBc + 8192 + ofs1);
    a0 += 64; b0 += 64;
    __syncthreads();

#pragma unroll
    for (int p = 0; p < 2; ++p) {
      const int pb = p * 4096;
      bf16x8 af[4], bfr[4];
#pragma unroll
      for (int i = 0; i < 4; ++i) {
        af[i]  = *(const bf16x8*)&lA[pb + (wm * 64 + i * 16 + rsel) * 32 + kchunkA];
        bfr[i] = *(const bf16x8*)&lB[pb + (wn * 64 + i * 16 + rsel) * 32 + kchunkA];
      }
#pragma unroll
      for (int i = 0; i < 4; ++i)
#pragma unroll
        for (int j = 0; j < 4; ++j)
          acc[i][j] = __builtin_amdgcn_mfma_f32_16x16x32_bf16(af[i], bfr[j], acc[i][j], 0, 0, 0);
    }
  }

  const int col = lane & 15;
  float bv4[4];
#pragma unroll
  for (int j = 0; j < 4; ++j) {
    const int ng = n0 + wn * 64 + j * 16 + col;
    bv4[j] = bz ? bz[ng] : 0.0f;
  }

  if (mode == 0) {
    char* stb = smem + w * 2176;      // 16 rows x 68 bf16 (136B stride)
    const int nc0 = n0 + wn * 64;
#pragma unroll
    for (int i = 0; i < 4; ++i) {     // FULLY UNROLLED (R3 lesson)
      __syncthreads();
      bf16_t* st = (bf16_t*)stb;
#pragma unroll
      for (int j = 0; j < 4; ++j)
#pragma unroll
        for (int r = 0; r < 4; ++r)
          st[(quad * 4 + r) * 68 + j * 16 + col] =
              __float2bfloat16(acc[i][j][r] * scale + bv4[j]);
      __syncthreads();
      const int row16 = lane >> 2, cseg = lane & 3;
      const long mrow = m0 + wm * 64 + i * 16 + row16;
      bf16_t* cp = (bf16_t*)Cv + (long)z * sC + mrow * ldC + nc0 + cseg * 16;
      const char* sp = stb + row16 * 136 + cseg * 32;
#pragma unroll
      for (int hh = 0; hh < 2; ++hh) {
        uint2 aa = *(const uint2*)(sp + hh * 16);
        uint2 bb = *(const uint2*)(sp + hh * 16 + 8);
        uint4 vv; vv.x = aa.x; vv.y = aa.y; vv.z = bb.x; vv.w = bb.y;
        *(uint4*)(cp + hh * 8) = vv;
      }
    }
  } else {
#pragma unroll
    for (int j = 0; j < 4; ++j) {
      const int ng = n0 + wn * 64 + j * 16 + col;
#pragma unroll
      for (int i = 0; i < 4; ++i) {
        const int mg = m0 + wm * 64 + i * 16 + quad * 4;
#pragma unroll
        for (int r = 0; r < 4; ++r)
          ((float*)Cv)[(long)z * sC + (long)(mg + r) * ldC + ng] =
              acc[i][j][r] * scale + bv4[j];
      }
    }
  }
}

// ---------------- fused q/k/v GEMM ----------------
// A = h [16384x512] bf16, B = wT + (z+1)*262144, bias = bias_cat + z*512.
// z 0,1: write fp8 e4m3 to o8 + z*8388608 (natural [t][n], n=512).
// z 2  : write fp8 e4m3 transposed to vT8[b][d][t] (d=512, t=2048 per batch).
__global__ __launch_bounds__(256) void gemm_qkv(
    const bf16_t* __restrict__ A, const bf16_t* __restrict__ wT,
    const float* __restrict__ bias_cat, u8* __restrict__ o8,
    u8* __restrict__ vT8)
{
  __shared__ __align__(16) char smem[32768];
  bf16_t* lA = (bf16_t*)smem;
  bf16_t* lB = (bf16_t*)(smem + 16384);
  const int z = blockIdx.z;
  const bf16_t* B = wT + (long)(z + 1) * 262144;
  const float* bz = bias_cat + (long)z * 512;
  const int K = 512;
  const int m0 = blockIdx.y * 128, n0 = blockIdx.x * 128;
  const int tid = threadIdx.x;
  const int w = tid >> 6, lane = tid & 63;
  const int wm = w >> 1, wn = w & 1;

  const int rr = tid >> 2;
  const int cc = (((tid & 3) ^ ((tid >> 3) & 3)) * 8);
  const bf16_t* a0 = A + (long)(m0 + rr) * K + cc;
  const bf16_t* b0 = B + (long)(n0 + rr) * K + cc;
  const long rowskip = (long)64 * K;

  char* lAc = (char*)lA;
  char* lBc = (char*)lB;
  const int ofs0 = w * 1024;
  const int ofs1 = 4096 + w * 1024;

  f32x4 acc[4][4] = {};
  const int quad = lane >> 4;
  const int rsel = lane & 15;
  const int swz = (rsel >> 1) & 3;
  const int kchunkA = (quad ^ swz) * 8;

  for (int kt = 0; kt < 8; ++kt) {    // K=512 / BK=64
    __syncthreads();
    cp16_to_lds(a0,                 lAc + ofs0);
    cp16_to_lds(a0 + rowskip,       lAc + ofs1);
    cp16_to_lds(a0 + 32,            lAc + 8192 + ofs0);
    cp16_to_lds(a0 + 32 + rowskip,  lAc + 8192 + ofs1);
    cp16_to_lds(b0,                 lBc + ofs0);
    cp16_to_lds(b0 + rowskip,       lBc + ofs1);
    cp16_to_lds(b0 + 32,            lBc + 8192 + ofs0);
    cp16_to_lds(b0 + 32 + rowskip,  lBc + 8192 + ofs1);
    a0 += 64; b0 += 64;
    __syncthreads();

#pragma unroll
    for (int p = 0; p < 2; ++p) {
      const int pb = p * 4096;
      bf16x8 af[4], bfr[4];
#pragma unroll
      for (int i = 0; i < 4; ++i) {
        af[i]  = *(const bf16x8*)&lA[pb + (wm * 64 + i * 16 + rsel) * 32 + kchunkA];
        bfr[i] = *(const bf16x8*)&lB[pb + (wn * 64 + i * 16 + rsel) * 32 + kchunkA];
      }
#pragma unroll
      for (int i = 0; i < 4; ++i)
#pragma unroll
        for (int j = 0; j < 4; ++j)
          acc[i][j] = __builtin_amdgcn_mfma_f32_16x16x32_bf16(af[i], bfr[j], acc[i][j], 0, 0, 0);
    }
  }

  const int col = lane & 15;
  float bv4[4];
#pragma unroll
  for (int j = 0; j < 4; ++j) bv4[j] = bz[n0 + wn * 64 + j * 16 + col];
  const int nc0 = n0 + wn * 64;

  if (z < 2) {
    // fp8 out: per-wave staging 16 t-rows x 72B (64 fp8 + pad)
    u8* stb = (u8*)(smem + w * 2176);
    u8* O = o8 + (long)z * 8388608;
#pragma unroll
    for (int i = 0; i < 4; ++i) {
      __syncthreads();
#pragma unroll
      for (int j = 0; j < 4; ++j) {
        uint pk = 0;
        pk = __builtin_amdgcn_cvt_pk_fp8_f32(acc[i][j][0] + bv4[j],
                                             acc[i][j][1] + bv4[j], pk, false);
        pk = __builtin_amdgcn_cvt_pk_fp8_f32(acc[i][j][2] + bv4[j],
                                             acc[i][j][3] + bv4[j], pk, true);
        stb[(quad * 4 + 0) * 72 + j * 16 + col] = (u8)(pk);
        stb[(quad * 4 + 1) * 72 + j * 16 + col] = (u8)(pk >> 8);
        stb[(quad * 4 + 2) * 72 + j * 16 + col] = (u8)(pk >> 16);
        stb[(quad * 4 + 3) * 72 + j * 16 + col] = (u8)(pk >> 24);
      }
      __syncthreads();
      const int trow = lane >> 2, seg = lane & 3;
      const long mrow = m0 + wm * 64 + i * 16 + trow;
      *(uint4*)(O + mrow * 512 + nc0 + seg * 16) =
          *(const uint4*)(stb + trow * 72 + seg * 16);
    }
  } else {
    // vT8 out: per-wave staging 16 d-rows x 72B (64 t fp8 + pad)
    u8* st8 = (u8*)(smem + w * 2176);
    const int bt = blockIdx.y >> 4;          // batch (16 y-blocks per batch)
    const int t0g = (m0 & 2047) + wm * 64;
#pragma unroll
    for (int j = 0; j < 4; ++j) {
      __syncthreads();
#pragma unroll
      for (int i = 0; i < 4; ++i) {
        uint pk = 0;
        pk = __builtin_amdgcn_cvt_pk_fp8_f32(acc[i][j][0] + bv4[j],
                                             acc[i][j][1] + bv4[j], pk, false);
        pk = __builtin_amdgcn_cvt_pk_fp8_f32(acc[i][j][2] + bv4[j],
                                             acc[i][j][3] + bv4[j], pk, true);
        *(uint*)&st8[col * 72 + i * 16 + quad * 4] = pk;
      }
      __syncthreads();
      const int drow = lane >> 2, seg = lane & 3;
      const int d = nc0 + j * 16 + drow;
      u8* dst = vT8 + ((long)(bt * 512 + d)) * 2048 + t0g;
      *(uint4*)(dst + seg * 16) = *(const uint4*)(st8 + drow * 72 + seg * 16);
    }
  }
}

// ---------------- generalized fp8 GEMM ----------------
// C = A8 * B8^T * scale.  A: M x K, B: N x K, fp8 e4m3, row strides = K bytes.
// BK=128 as 2 panels of (128 rows x 64B). bf16 out via LDS-staged stores.
__global__ __launch_bounds__(256) void gemm_fp8(
    const u8* __restrict__ A, const u8* __restrict__ B,
    bf16_t* __restrict__ C, float scale, int K,
    long sA, long sB, long sC, int ldC)
{
  __shared__ __align__(16) char smem[32768];
  const int z = blockIdx.z;
  A += (long)z * sA;
  B += (long)z * sB;
  const int m0 = blockIdx.y * 128, n0 = blockIdx.x * 128;
  const int tid = threadIdx.x;
  const int w = tid >> 6, lane = tid & 63;
  const int wm = w >> 1, wn = w & 1;

  const int rr = tid >> 2;
  const int ccB = (((tid & 3) ^ ((tid >> 3) & 3)) * 16);   // byte ofs in 64B row
  const u8* a0 = A + (long)(m0 + rr) * K + ccB;
  const u8* b0 = B + (long)(n0 + rr) * K + ccB;
  const long rowskip = (long)64 * K;

  char* lAc = smem;
  char* lBc = smem + 16384;
  const int ofs0 = w * 1024;
  const int ofs1 = 4096 + w * 1024;

  f32x4 acc[4][4] = {};
  const int quad = lane >> 4;
  const int rsel = lane & 15;
  const int swz = (rsel >> 1) & 3;

  const int nkt = K >> 7;             // BK=128
  for (int kt = 0; kt < nkt; ++kt) {
    __syncthreads();
    cp16_to_lds(a0,                  lAc + ofs0);
    cp16_to_lds(a0 + rowskip,        lAc + ofs1);
    cp16_to_lds(a0 + 64,             lAc + 8192 + ofs0);
    cp16_to_lds(a0 + 64 + rowskip,   lAc + 8192 + ofs1);
    cp16_to_lds(b0,                  lBc + ofs0);
    cp16_to_lds(b0 + rowskip,        lBc + ofs1);
    cp16_to_lds(b0 + 64,             lBc + 8192 + ofs0);
    cp16_to_lds(b0 + 64 + rowskip,   lBc + 8192 + ofs1);
    a0 += 128; b0 += 128;
    __syncthreads();

#pragma unroll
    for (int p = 0; p < 2; ++p) {
      const int pb = p * 8192;
#pragma unroll
      for (int ks = 0; ks < 2; ++ks) {
        const int gr = ((ks * 2 + (quad >> 1)) ^ swz) * 16 + (quad & 1) * 8;
        long av[4], bv[4];
#pragma unroll
        for (int i = 0; i < 4; ++i) {
          av[i] = *(const long*)(lAc + pb + (wm * 64 + i * 16 + rsel) * 64 + gr);
          bv[i] = *(const long*)(lBc + pb + (wn * 64 + i * 16 + rsel) * 64 + gr);
        }
#pragma unroll
        for (int i = 0; i < 4; ++i)
#pragma unroll
          for (int j = 0; j < 4; ++j)
            acc[i][j] = __builtin_amdgcn_mfma_f32_16x16x32_fp8_fp8(av[i], bv[j], acc[i][j], 0, 0, 0);
      }
    }
  }

  // epilogue: bf16 out, LDS-staged
  const int col = lane & 15;
  char* stb = smem + w * 2176;
  const int nc0 = n0 + wn * 64;
#pragma unroll
  for (int i = 0; i < 4; ++i) {
    __syncthreads();
    bf16_t* st = (bf16_t*)stb;
#pragma unroll
    for (int j = 0; j < 4; ++j)
#pragma unroll
      for (int r = 0; r < 4; ++r)
        st[(quad * 4 + r) * 68 + j * 16 + col] =
            __float2bfloat16(acc[i][j][r] * scale);
    __syncthreads();
    const int row16 = lane >> 2, cseg = lane & 3;
    const long mrow = m0 + wm * 64 + i * 16 + row16;
    bf16_t* cp = C + (long)z * sC + mrow * ldC + nc0 + cseg * 16;
    const char* sp = stb + row16 * 136 + cseg * 32;
#pragma unroll
    for (int hh = 0; hh < 2; ++hh) {
      uint2 aa = *(const uint2*)(sp + hh * 16);
      uint2 bb = *(const uint2*)(sp + hh * 16 + 8);
      uint4 vv; vv.x = aa.x; vv.y = aa.y; vv.z = bb.x; vv.w = bb.y;
      *(uint4*)(cp + hh * 8) = vv;
    }
  }
}

// ---------------- small kernels ----------------
__global__ __launch_bounds__(256) void weight_prep(
    const float* __restrict__ w0, const float* __restrict__ w1,
    const float* __restrict__ w2, const float* __restrict__ w3,
    const float* __restrict__ w4,
    const float* __restrict__ bq, const float* __restrict__ bk,
    const float* __restrict__ bv,
    bf16_t* __restrict__ outT, float* __restrict__ bias_cat)
{
  const int z = blockIdx.z;
  const int N = (z == 4) ? 256 : 512;
  if (z == 4 && blockIdx.y >= 4) return;
  const float* in = (z == 0) ? w0 : (z == 1) ? w1 : (z == 2) ? w2 : (z == 3) ? w3 : w4;
  bf16_t* out = outT + (long)z * 262144;
  const int k0 = blockIdx.x * 64, n0 = blockIdx.y * 64;
  __shared__ bf16_t tile[64 * 66];
  const int tid = threadIdx.x;
  const int r = tid >> 2, c4 = tid & 3;
  const float* src = in + (long)(k0 + r) * N + n0 + c4 * 16;
  uint* dst = (uint*)&tile[r * 66 + c4 * 16];
  float4 f0 = ((const float4*)src)[0], f1 = ((const float4*)src)[1];
  float4 f2 = ((const float4*)src)[2], f3 = ((const float4*)src)[3];
  dst[0] = pk2(f0.x, f0.y); dst[1] = pk2(f0.z, f0.w);
  dst[2] = pk2(f1.x, f1.y); dst[3] = pk2(f1.z, f1.w);
  dst[4] = pk2(f2.x, f2.y); dst[5] = pk2(f2.z, f2.w);
  dst[6] = pk2(f3.x, f3.y); dst[7] = pk2(f3.z, f3.w);
  __syncthreads();
  bf16_t* og = out + (long)(n0 + r) * 512 + k0 + c4 * 16;
  uint ov[8];
#pragma unroll
  for (int j = 0; j < 16; j += 2) {
    const ushort lo = *(const ushort*)&tile[(c4 * 16 + j) * 66 + r];
    const ushort hi = *(const ushort*)&tile[(c4 * 16 + j + 1) * 66 + r];
    ov[j >> 1] = ((uint)hi << 16) | lo;
  }
  uint4 o0, o1;
  o0.x = ov[0]; o0.y = ov[1]; o0.z = ov[2]; o0.w = ov[3];
  o1.x = ov[4]; o1.y = ov[5]; o1.z = ov[6]; o1.w = ov[7];
  ((uint4*)og)[0] = o0;
  ((uint4*)og)[1] = o1;
  if (z >= 1 && z <= 3 && blockIdx.x == 0 && blockIdx.y == 0) {
    const float* bs = (z == 1) ? bq : (z == 2) ? bk : bv;
    bias_cat[(z - 1) * 512 + tid] = bs[tid];
    bias_cat[(z - 1) * 512 + 256 + tid] = bs[256 + tid];
  }
}

__global__ __launch_bounds__(256) void cast_bf16_v(
    const float4* __restrict__ in, uint2* __restrict__ o, int n4) {
  const int i = blockIdx.x * 256 + threadIdx.x;
  if (i < n4) {
    const float4 f = in[i];
    uint2 r; r.x = pk2(f.x, f.y); r.y = pk2(f.z, f.w);
    o[i] = r;
  }
}

// in-place LayerNorm(512)+ReLU, one wave per row, 8 bf16/lane, shuffle-only.
__global__ __launch_bounds__(256) void ln_relu_h(
    bf16_t* __restrict__ X, const float* __restrict__ g, const float* __restrict__ b)
{
  const int tid = threadIdx.x;
  const int lane = tid & 63, w = tid >> 6;
  const long row = (long)blockIdx.x * 4 + w;
  bf16_t* xp = X + row * 512 + lane * 8;
  const uint4 pkv = *(const uint4*)xp;
  const uint va[4] = {pkv.x, pkv.y, pkv.z, pkv.w};
  float v[8];
  float s = 0.0f, q = 0.0f;
#pragma unroll
  for (int i = 0; i < 4; ++i) {
    v[2 * i] = bflo(va[i]); v[2 * i + 1] = bfhi(va[i]);
    s += v[2 * i] + v[2 * i + 1];
    q += v[2 * i] * v[2 * i] + v[2 * i + 1] * v[2 * i + 1];
  }
  for (int o = 32; o; o >>= 1) { s += __shfl_down(s, o); q += __shfl_down(q, o); }
  s = __shfl(s, 0); q = __shfl(q, 0);
  const float mu = s * (1.0f / 512.0f);
  const float rs = rsqrtf(q * (1.0f / 512.0f) - mu * mu + 1e-5f);
  const float4 g0 = ((const float4*)(g + lane * 8))[0], g1 = ((const float4*)(g + lane * 8))[1];
  const float4 b0 = ((const float4*)(b + lane * 8))[0], b1 = ((const float4*)(b + lane * 8))[1];
  const float gg[8] = {g0.x, g0.y, g0.z, g0.w, g1.x, g1.y, g1.z, g1.w};
  const float bb[8] = {b0.x, b0.y, b0.z, b0.w, b1.x, b1.y, b1.z, b1.w};
  uint ov[4];
#pragma unroll
  for (int i = 0; i < 4; ++i) {
    const float y0 = fmaxf((v[2 * i] - mu) * rs * gg[2 * i] + bb[2 * i], 0.0f);
    const float y1 = fmaxf((v[2 * i + 1] - mu) * rs * gg[2 * i + 1] + bb[2 * i + 1], 0.0f);
    ov[i] = pk2(y0, y1);
  }
  uint4 st; st.x = ov[0]; st.y = ov[1]; st.z = ov[2]; st.w = ov[3];
  *(uint4*)xp = st;
}

// per row: softmax over 2048 (read sc bf16), then * exp(-5*dist) * (!mask),
// write attn8 = fp8 e4m3 of (val * 256).
__global__ __launch_bounds__(256) void softmax_adj(
    const bf16_t* __restrict__ SC, u8* __restrict__ A8,
    const float* __restrict__ coords, const int* __restrict__ mask)
{
  const int bs = blockIdx.x;
  const int b = bs >> 11, s = bs & 2047;
  const long base = (long)bs * 2048;
  const int tid = threadIdx.x;
  const uint4 pkv = *(const uint4*)(SC + base + tid * 8);
  const uint va[4] = {pkv.x, pkv.y, pkv.z, pkv.w};
  float rv[8];
  float mx = -3.0e38f;
#pragma unroll
  for (int i = 0; i < 4; ++i) {
    rv[2 * i] = bflo(va[i]); rv[2 * i + 1] = bfhi(va[i]);
    mx = fmaxf(mx, fmaxf(rv[2 * i], rv[2 * i + 1]));
  }
  for (int o = 32; o; o >>= 1) mx = fmaxf(mx, __shfl_down(mx, o));
  __shared__ float sm[8];
  const int w = tid >> 6, lane = tid & 63;
  if (!lane) sm[w] = mx;
  __syncthreads();
  mx = fmaxf(fmaxf(sm[0], sm[1]), fmaxf(sm[2], sm[3]));
  float sum = 0.0f;
#pragma unroll
  for (int i = 0; i < 8; ++i) { rv[i] = __expf(rv[i] - mx); sum += rv[i]; }
  for (int o = 32; o; o >>= 1) sum += __shfl_down(sum, o);
  if (!lane) sm[4 + w] = sum;
  __syncthreads();
  const float inv = 256.0f / (sm[4] + sm[5] + sm[6] + sm[7]);   // x256 fp8 scale
  const float px = coords[((long)b * 2048 + s) * 3];
  const float py = coords[((long)b * 2048 + s) * 3 + 1];
  const int t0 = tid * 8;
  const float* cb = coords + ((long)b * 2048 + t0) * 3;
  const int* mb = mask + b * 2048 + t0;
  float ov[8];
#pragma unroll
  for (int i = 0; i < 8; ++i) {
    const float dx = px - cb[i * 3], dy = py - cb[i * 3 + 1];
    const float adj = __expf(-5.0f * sqrtf(dx * dx + dy * dy));
    ov[i] = mb[i] ? 0.0f : rv[i] * inv * adj;
  }
  uint2 st;
  uint p0 = 0, p1 = 0;
  p0 = __builtin_amdgcn_cvt_pk_fp8_f32(ov[0], ov[1], p0, false);
  p0 = __builtin_amdgcn_cvt_pk_fp8_f32(ov[2], ov[3], p0, true);
  p1 = __builtin_amdgcn_cvt_pk_fp8_f32(ov[4], ov[5], p1, false);
  p1 = __builtin_amdgcn_cvt_pk_fp8_f32(ov[6], ov[7], p1, true);
  st.x = p0; st.y = p1;
  *(uint2*)(A8 + base + t0) = st;
}

// LayerNorm(256)+ReLU on f32 rows, masked accumulate into pooled_acc[b][256]
__global__ __launch_bounds__(256) void ln2_pool(
    const float* __restrict__ X, const float* __restrict__ g, const float* __restrict__ bt,
    const int* __restrict__ mask, float* __restrict__ pacc)
{
  const int tid = threadIdx.x;
  const int row0 = blockIdx.x * 16;
  const int w = tid >> 6, lane = tid & 63;
  __shared__ float sm[8];
  const float gv = g[tid], bv = bt[tid];
  float acc = 0.0f;
  for (int r = 0; r < 16; ++r) {
    const int row = row0 + r;
    const float x = X[(long)row * 256 + tid];
    float s = x, q = x * x;
    for (int o = 32; o; o >>= 1) { s += __shfl_down(s, o); q += __shfl_down(q, o); }
    if (!lane) { sm[w] = s; sm[4 + w] = q; }
    __syncthreads();
    const float S = sm[0] + sm[1] + sm[2] + sm[3];
    const float Q = sm[4] + sm[5] + sm[6] + sm[7];
    const float mu = S * (1.0f / 256.0f);
    const float rs = rsqrtf(Q * (1.0f / 256.0f) - mu * mu + 1e-5f);
    const float y = fmaxf((x - mu) * rs * gv + bv, 0.0f);
    if (!mask[row]) acc += y;
    __syncthreads();
  }
  atomicAdd(&pacc[(row0 >> 11) * 256 + tid], acc);
}

// counts, pooled=acc/count -> out[80..], relu(pooled@w1+b1)@w2+b2 -> out[0..80)
__global__ __launch_bounds__(256) void classifier_k(
    const float* __restrict__ pacc, const int* __restrict__ mask,
    const float* __restrict__ w1, const float* __restrict__ b1,
    const float* __restrict__ w2, const float* __restrict__ b2,
    float* __restrict__ out)
{
  const int tid = threadIdx.x;
  __shared__ float pooled[2048];
  __shared__ float hidden[1024];
  __shared__ float cnt[8];
  if (tid < 8) cnt[tid] = 0.0f;
  __syncthreads();
  {
    const int* mb = mask + tid * 64;
    int c = 0;
#pragma unroll 8
    for (int i = 0; i < 64; ++i) c += mb[i] ? 0 : 1;
    atomicAdd(&cnt[tid >> 5], (float)c);
  }
  __syncthreads();
  for (int i = tid; i < 2048; i += 256) {
    const float p = pacc[i] / fmaxf(cnt[i >> 8], 1e-9f);
    pooled[i] = p;
    out[80 + i] = p;
  }
  __syncthreads();
  for (int o = tid; o < 1024; o += 256) {
    const int bb = o >> 7, j = o & 127;
    float s = b1[j];
    const float* pb = pooled + bb * 256;
    for (int c = 0; c < 256; ++c) s += pb[c] * w1[c * 128 + j];
    hidden[o] = fmaxf(s, 0.0f);
  }
  __syncthreads();
  if (tid < 80) {
    const int bb = tid / 10, j = tid - bb * 10;
    float s = b2[j];
    const float* hb = hidden + bb * 128;
    for (int c = 0; c < 128; ++c) s += hb[c] * w2[c * 10 + j];
    out[tid] = s;
  }
}

extern "C" void kernel_launch(void* const* d_in, const int* in_sizes, int n_in,
                              void* d_out, int out_size, void* d_ws, size_t ws_size,
                              hipStream_t stream)
{
  const float* lf   = (const float*)d_in[0];
  const float* co   = (const float*)d_in[1];
  const int*   mk   = (const int*)d_in[2];
  const float* wenc = (const float*)d_in[3];
  const float* benc = (const float*)d_in[4];
  const float* g1   = (const float*)d_in[5];
  const float* be1  = (const float*)d_in[6];
  const float* wq   = (const float*)d_in[7];
  const float* bq   = (const float*)d_in[8];
  const float* wk   = (const float*)d_in[9];
  const float* bk   = (const float*)d_in[10];
  const float* wv   = (const float*)d_in[11];
  const float* bvp  = (const float*)d_in[12];
  const float* wbn  = (const float*)d_in[13];
  const float* bbn  = (const float*)d_in[14];
  const float* g2   = (const float*)d_in[15];
  const float* be2  = (const float*)d_in[16];
  const float* w1   = (const float*)d_in[17];
  const float* b1   = (const float*)d_in[18];
  const float* w2   = (const float*)d_in[19];
  const float* b2   = (const float*)d_in[20];
  float* out = (float*)d_out;
  char* ws = (char*)d_ws;

  // Layout (bytes). Reuse: hg overlays featb (dead after enc GEMM);
  // bnp overlays q8/k8 (dead after scores); pacc overlays vT8 head (dead after av).
  bf16_t* featb = (bf16_t*)(ws + 0);              // 16 MB
  bf16_t* wT    = (bf16_t*)(ws + 16777216);       // 5 x 512KB slots
  bf16_t* wencT = wT;
  bf16_t* wbnT  = wT + 4 * 262144;
  float*  bias_cat = (float*)(ws + 19398656);     // 8 KB
  bf16_t* h     = (bf16_t*)(ws + 19406848);       // 16 MB -> ends 36184064
  u8*     q8    = (u8*)(ws + 36184064);           // 16 MB (q8, k8) -> 52961280
  u8*     vT8   = (u8*)(ws + 52961280);           // 8 MB -> 61349888
  bf16_t* sc    = (bf16_t*)(ws + 61349888);       // 64 MB -> 128458752
  u8*     at8   = (u8*)(ws + 128458752);          // 32 MB -> 162013184
  bf16_t* hg    = (bf16_t*)(ws + 0);              // reuse featb
  float*  bnp   = (float*)(ws + 36184064);        // reuse q8/k8 (16 MB f32)
  float*  pacc  = (float*)(ws + 52961280);        // reuse vT8 head (8 KB)

  if (ws_size < 162013184) return;  // fail visibly rather than fault

  cast_bf16_v<<<8192, 256, 0, stream>>>((const float4*)lf, (uint2*)featb, 2097152);
  weight_prep<<<dim3(8, 8, 5), 256, 0, stream>>>(wenc, wq, wk, wv, wbn, bq, bk, bvp,
                                                 wT, bias_cat);

  // h_pre = feat @ w_enc + b_enc
  gemm_bt<<<dim3(4, 128, 1), 256, 0, stream>>>(featb, wencT, h, benc, 0, 1.0f, 512,
                                               0, 0, 0, 512, 0);
  ln_relu_h<<<4096, 256, 0, stream>>>(h, g1, be1);
  // q,k (fp8 natural) + v (fp8 transposed) in one launch
  gemm_qkv<<<dim3(4, 128, 3), 256, 0, stream>>>(h, wT, bias_cat, q8, vT8);
  // scores[b] = q_b k_b^T / sqrt(512)  (fp8 in, bf16 out)
  gemm_fp8<<<dim3(16, 16, 8), 256, 0, stream>>>(q8, q8 + 8388608, sc,
                                                0.044194173824159216f, 512,
                                                1048576, 1048576, 4194304, 2048);
  // softmax + adj + mask -> attn8 (fp8 x256)
  softmax_adj<<<16384, 256, 0, stream>>>(sc, at8, co, mk);
  // hg[b] = attn_b @ v_b  (fp8 in, bf16 out, scale 1/256)
  gemm_fp8<<<dim3(4, 16, 8), 256, 0, stream>>>(at8, vT8, hg, 0.00390625f, 2048,
                                               4194304, 1048576, 1048576, 512);
  // bn_pre = hg @ w_bn + b_bn  (f32 out)
  gemm_bt<<<dim3(2, 128, 1), 256, 0, stream>>>(hg, wbnT, bnp, bbn, 0, 1.0f, 512,
                                               0, 0, 0, 256, 2);
  hipMemsetAsync(pacc, 0, 8192, stream);
  ln2_pool<<<1024, 256, 0, stream>>>(bnp, g2, be2, mk, pacc);
  classifier_k<<<1, 256, 0, stream>>>(pacc, mk, w1, b1, w2, b2, out);
}